// Round 1
// baseline (150.279 us; speedup 1.0000x reference)
//
#include <hip/hip_runtime.h>

typedef __bf16 bf16x8 __attribute__((ext_vector_type(8)));
typedef float  f32x4  __attribute__((ext_vector_type(4)));

// Sizes: B=64, C=128, ORI=6, HW=28*28=784, NB=4, BS=32
// xh strides (floats): b:1204224, c:9408, ori:1568, hw:2, ri:1
// flattened position space per (ori,nb): P = b*784 + hw, 0..50175 = 196 tiles of 256

static __device__ __forceinline__ unsigned short bf16bits(float f) {
  __bf16 h = (__bf16)f;
  return __builtin_bit_cast(unsigned short, h);
}

// ---------------- weight prep: build W1t/W2t [nb][layer][n=64][k=64] bf16 ----------------
// combined real matrix of the complex block matmul, transposed to [n_out][k_in]:
//  n<32,k<32:  wr[k][n]   n<32,k>=32: -wi[k-32][n]
//  n>=32,k<32: wi[k][n-32] n>=32,k>=32: wr[k-32][n-32]
__global__ void prep_weights(const float* __restrict__ w1, const float* __restrict__ w2,
                             unsigned short* __restrict__ wg) {
  const int e = blockIdx.x * 256 + threadIdx.x;      // 0..32767
  const int nb    = e >> 13;
  const int layer = (e >> 12) & 1;
  const int n = (e >> 6) & 63;
  const int k = e & 63;
  const float* w = layer ? w2 : w1;
  const int kk = k & 31, nn = n & 31;
  float v;
  if (n < 32) {
    v = (k < 32) ?  w[((0 * 4 + nb) * 32 + kk) * 32 + nn]
                 : -w[((1 * 4 + nb) * 32 + kk) * 32 + nn];
  } else {
    v = (k < 32) ?  w[((1 * 4 + nb) * 32 + kk) * 32 + nn]
                 :  w[((0 * 4 + nb) * 32 + kk) * 32 + nn];
  }
  wg[e] = bf16bits(v);
}

// ---------------- lowpass: xl_out = xl * w_ll (broadcast over batch) ----------------
__global__ void ll_kernel(const float* __restrict__ xl, const float* __restrict__ wll,
                          float* __restrict__ out) {
  const int i = blockIdx.x * 256 + threadIdx.x;      // float4 index, 1605632 total
  const float4 x = reinterpret_cast<const float4*>(xl)[i];
  const float4 w = reinterpret_cast<const float4*>(wll)[i % 25088]; // 100352 floats / 4
  float4 o;
  o.x = x.x * w.x; o.y = x.y * w.y; o.z = x.z * w.z; o.w = x.w * w.w;
  reinterpret_cast<float4*>(out)[i] = o;
}

// ---------------- main xh kernel ----------------
// grid = (ORI*NB) * 196;  block = 256 (4 waves)
// each WG: one (ori, nb, 256-position tile); GEMMs computed swapped: D[n][p] = W * X^T
__global__ __launch_bounds__(256, 3)
void xh_kernel(const float* __restrict__ xh, const unsigned short* __restrict__ wg,
               const float* __restrict__ b1, const float* __restrict__ b2,
               float* __restrict__ oxh) {
  __shared__ __align__(16) unsigned short Xs[256 * 64];   // X tile -> reused as H tile (bf16)
  __shared__ __align__(16) unsigned short Ws[2 * 64 * 64];
  __shared__ __align__(16) float Bs[128];

  const int t = threadIdx.x;
  const int bi = blockIdx.x;
  const int mt  = bi % 196;
  const int snb = bi / 196;
  const int ori = snb >> 2;
  const int nb  = snb & 3;
  const int p0 = mt << 8;

  // stage biases: Bs[layer*64 + n], n<32 -> real part bias, n>=32 -> imag
  if (t < 128) {
    const int layer = t >> 6, n = t & 63;
    const float* bsrc = layer ? b2 : b1;
    Bs[t] = bsrc[((n >> 5) * 4 + nb) * 32 + (n & 31)];
  }

  // stage weights -> LDS, XOR-swizzled 16B groups: byte = layer*8192 + n*128 + (g ^ ((n>>1)&7))*16
  {
    const unsigned short* wgn = wg + nb * 8192;
#pragma unroll
    for (int it = 0; it < 4; ++it) {
      const int idx = it * 256 + t;            // 0..1023 16B-chunks
      const int layer = idx >> 9;
      const int n = (idx >> 3) & 63;
      const int g = idx & 7;
      const uint4 v = *reinterpret_cast<const uint4*>(wgn + layer * 4096 + n * 64 + g * 8);
      char* dst = reinterpret_cast<char*>(Ws) + layer * 8192 + n * 128 + ((g ^ ((n >> 1) & 7)) * 16);
      *reinterpret_cast<uint4*>(dst) = v;
    }
  }

  // stage X tile: Xs[p][k] bf16, k = ri*32 + c_local, swizzled same as weights (by row p)
  {
    const float* xb = xh + (size_t)(nb * 32) * 9408 + ori * 1568;
#pragma unroll
    for (int it = 0; it < 8; ++it) {
      const int idx = it * 256 + t;            // 0..2047
      const int c = (idx >> 7) * 2;            // even channel of the pair
      const int p = (idx & 127) * 2;           // even local position
      const int P = p0 + p;
      const int bb = P / 784;
      const int hw = P - bb * 784;             // even; P,P+1 share bb (784 even)
      const float* src = xb + (size_t)bb * 1204224 + c * 9408 + hw * 2;
      const float4 vA = *reinterpret_cast<const float4*>(src);          // ch c : re(p),im(p),re(p+1),im(p+1)
      const float4 vB = *reinterpret_cast<const float4*>(src + 9408);   // ch c+1
      const int g0 = c >> 3;
      const int off = (c & 7) * 2;
      const int s0 = (p >> 1) & 7;             // same for rows p and p+1
      char* base = reinterpret_cast<char*>(Xs);
      *reinterpret_cast<unsigned int*>(base + p * 128 + ((g0 ^ s0) * 16) + off) =
          (unsigned int)bf16bits(vA.x) | ((unsigned int)bf16bits(vB.x) << 16);
      *reinterpret_cast<unsigned int*>(base + p * 128 + (((g0 + 4) ^ s0) * 16) + off) =
          (unsigned int)bf16bits(vA.y) | ((unsigned int)bf16bits(vB.y) << 16);
      *reinterpret_cast<unsigned int*>(base + (p + 1) * 128 + ((g0 ^ s0) * 16) + off) =
          (unsigned int)bf16bits(vA.z) | ((unsigned int)bf16bits(vB.z) << 16);
      *reinterpret_cast<unsigned int*>(base + (p + 1) * 128 + (((g0 + 4) ^ s0) * 16) + off) =
          (unsigned int)bf16bits(vA.w) | ((unsigned int)bf16bits(vB.w) << 16);
    }
  }
  __syncthreads();

  const int lane = t & 63;
  const int wv = t >> 6;               // wave owns positions [wv*64, wv*64+64)
  const int lr = lane & 15;
  const int lg = lane >> 4;            // 0..3

  // ---- layer 1: D1[n1][p] = W1t (A) * X^T (B) ----
  f32x4 acc[4][4];
#pragma unroll
  for (int mi = 0; mi < 4; ++mi)
#pragma unroll
    for (int ni = 0; ni < 4; ++ni)
      acc[mi][ni] = (f32x4){0.f, 0.f, 0.f, 0.f};

#pragma unroll
  for (int ks = 0; ks < 2; ++ks) {
    bf16x8 wf[4], xf[4];
#pragma unroll
    for (int mi = 0; mi < 4; ++mi) {
      const int n = mi * 16 + lr;
      wf[mi] = *reinterpret_cast<const bf16x8*>(reinterpret_cast<const char*>(Ws)
                 + n * 128 + (((ks * 4 + lg) ^ ((n >> 1) & 7)) * 16));
    }
#pragma unroll
    for (int ni = 0; ni < 4; ++ni) {
      const int p = wv * 64 + ni * 16 + lr;
      xf[ni] = *reinterpret_cast<const bf16x8*>(reinterpret_cast<const char*>(Xs)
                 + p * 128 + (((ks * 4 + lg) ^ ((p >> 1) & 7)) * 16));
    }
#pragma unroll
    for (int mi = 0; mi < 4; ++mi)
#pragma unroll
      for (int ni = 0; ni < 4; ++ni)
        acc[mi][ni] = __builtin_amdgcn_mfma_f32_16x16x32_bf16(wf[mi], xf[ni], acc[mi][ni], 0, 0, 0);
  }

  // ---- epilogue 1: H = relu(D1 + b1), write back into Xs as H[p][n1] (wave-private rows) ----
#pragma unroll
  for (int mi = 0; mi < 4; ++mi) {
    const f32x4 bv = *reinterpret_cast<const f32x4*>(&Bs[mi * 16 + lg * 4]);
    const int gH = mi * 2 + (lg >> 1);
    const int offH = (lg & 1) * 8;
#pragma unroll
    for (int ni = 0; ni < 4; ++ni) {
      const int p = wv * 64 + ni * 16 + lr;
      const float h0 = fmaxf(acc[mi][ni][0] + bv[0], 0.f);
      const float h1 = fmaxf(acc[mi][ni][1] + bv[1], 0.f);
      const float h2 = fmaxf(acc[mi][ni][2] + bv[2], 0.f);
      const float h3 = fmaxf(acc[mi][ni][3] + bv[3], 0.f);
      uint2 u;
      u.x = (unsigned int)bf16bits(h0) | ((unsigned int)bf16bits(h1) << 16);
      u.y = (unsigned int)bf16bits(h2) | ((unsigned int)bf16bits(h3) << 16);
      char* dst = reinterpret_cast<char*>(Xs) + p * 128 + ((gH ^ ((p >> 1) & 7)) * 16) + offH;
      *reinterpret_cast<uint2*>(dst) = u;
    }
  }
  __syncthreads();

  // ---- layer 2: D2[n2][p] = W2t (A) * H^T (B) ----
  f32x4 acc2[4][4];
#pragma unroll
  for (int mi = 0; mi < 4; ++mi)
#pragma unroll
    for (int ni = 0; ni < 4; ++ni)
      acc2[mi][ni] = (f32x4){0.f, 0.f, 0.f, 0.f};

#pragma unroll
  for (int ks = 0; ks < 2; ++ks) {
    bf16x8 wf[4], hf[4];
#pragma unroll
    for (int mi = 0; mi < 4; ++mi) {
      const int n = mi * 16 + lr;
      wf[mi] = *reinterpret_cast<const bf16x8*>(reinterpret_cast<const char*>(Ws)
                 + 8192 + n * 128 + (((ks * 4 + lg) ^ ((n >> 1) & 7)) * 16));
    }
#pragma unroll
    for (int ni = 0; ni < 4; ++ni) {
      const int p = wv * 64 + ni * 16 + lr;
      hf[ni] = *reinterpret_cast<const bf16x8*>(reinterpret_cast<const char*>(Xs)
                 + p * 128 + (((ks * 4 + lg) ^ ((p >> 1) & 7)) * 16));
    }
#pragma unroll
    for (int mi = 0; mi < 4; ++mi)
#pragma unroll
      for (int ni = 0; ni < 4; ++ni)
        acc2[mi][ni] = __builtin_amdgcn_mfma_f32_16x16x32_bf16(wf[mi], hf[ni], acc2[mi][ni], 0, 0, 0);
  }

  // ---- epilogue 2: out[b][nb*32+c][ori][hw][0..1] = (re, im); same lane holds both -> float2 ----
  float* ob = oxh + (size_t)(nb * 32) * 9408 + ori * 1568;
#pragma unroll
  for (int ni = 0; ni < 4; ++ni) {
    const int p = wv * 64 + ni * 16 + lr;
    const int P = p0 + p;
    const int bb = P / 784;
    const int hw = P - bb * 784;
    float* obase = ob + (size_t)bb * 1204224 + hw * 2;
#pragma unroll
    for (int mi = 0; mi < 2; ++mi) {
      const f32x4 bre = *reinterpret_cast<const f32x4*>(&Bs[64 + mi * 16 + lg * 4]);
      const f32x4 bim = *reinterpret_cast<const f32x4*>(&Bs[64 + (mi + 2) * 16 + lg * 4]);
#pragma unroll
      for (int j = 0; j < 4; ++j) {
        const int c = mi * 16 + lg * 4 + j;
        float2 v;
        v.x = acc2[mi][ni][j] + bre[j];
        v.y = acc2[mi + 2][ni][j] + bim[j];
        *reinterpret_cast<float2*>(obase + (size_t)c * 9408) = v;
      }
    }
  }
}

extern "C" void kernel_launch(void* const* d_in, const int* in_sizes, int n_in,
                              void* d_out, int out_size, void* d_ws, size_t ws_size,
                              hipStream_t stream) {
  (void)in_sizes; (void)n_in; (void)out_size; (void)ws_size;
  const float* xl  = (const float*)d_in[0];
  const float* xh  = (const float*)d_in[1];
  const float* wll = (const float*)d_in[2];
  const float* w1  = (const float*)d_in[3];
  const float* w2  = (const float*)d_in[4];
  const float* b1  = (const float*)d_in[5];
  const float* b2  = (const float*)d_in[6];
  float* out = (float*)d_out;
  unsigned short* wg = (unsigned short*)d_ws;   // 65536 bytes used

  prep_weights<<<128, 256, 0, stream>>>(w1, w2, wg);
  ll_kernel<<<6272, 256, 0, stream>>>(xl, wll, out);
  xh_kernel<<<6 * 4 * 196, 256, 0, stream>>>(xh, wg, b1, b2, out + 6422528);
}